// Round 5
// baseline (20681.587 us; speedup 1.0000x reference)
//
#include <hip/hip_runtime.h>
#include <stdint.h>

#define T_LEN 4096
#define HID   400
#define G4    1600
#define KDIM  300
#define RING  32

__device__ __forceinline__ float fsig(float x){ return 1.f/(1.f + __expf(-x)); }
__device__ __forceinline__ float ftanh(float x){ float e = __expf(2.f*x); return 1.f - 2.f/(e+1.f); }

// ---- hang-proof dual-path handshake primitives ----
// Fast path: 64b atomic RMW (+0) at WORKGROUP scope. Atomics execute at the
// XCD's TCC (L1 has no atomic units), so this reads the true L2-resident value
// by construction -- no cache-bit assumptions. Publisher's plain store reaches
// the local L2 via the write-through L1. Valid when producer+consumer share an
// XCD (runtime-gated below).
// Safe path: agent-scope atomics (the round-2-proven, passing primitive).
// Every publish writes BOTH rings; every poll tries fast (bounded), then safe
// (unbounded). Tags self-validate (packed {tag,value} u64) -> no fences.
__device__ __forceinline__ unsigned long long l2_probe(unsigned long long* p){
  return __hip_atomic_fetch_add(p, 0ull, __ATOMIC_RELAXED, __HIP_MEMORY_SCOPE_WORKGROUP);
}
__device__ __forceinline__ void publish_dual(unsigned long long* fast, unsigned long long* safe,
                                             unsigned tag, float v){
  union{unsigned u; float f;} c; c.f = v;
  unsigned long long pk = ((unsigned long long)tag << 32) | (unsigned long long)c.u;
  *(volatile unsigned long long*)fast = pk;   // write-through -> local XCD L2
  __hip_atomic_store(safe, pk, __ATOMIC_RELAXED, __HIP_MEMORY_SCOPE_AGENT);
}
__device__ __forceinline__ float poll_dual(unsigned long long* fast, const unsigned long long* safe,
                                           unsigned tag){
  for (int k = 0; k < 24; ++k){
    unsigned long long x = l2_probe(fast);
    if ((unsigned)(x >> 32) == tag){
      union{unsigned u; float f;} c; c.u = (unsigned)x; return c.f;
    }
  }
  unsigned long long x;
  do { x = __hip_atomic_load(safe, __ATOMIC_RELAXED, __HIP_MEMORY_SCOPE_AGENT); }
  while ((unsigned)(x >> 32) != tag);
  union{unsigned u; float f;} c; c.u = (unsigned)x; return c.f;
}

// ---------------- control-block zeroing (ctl words + both ring pairs) ----------------
// Runs before kpipe every invocation -> zero dependence on harness poison.
__global__ void kzero(unsigned long long* __restrict__ p, int n){
  int i = blockIdx.x*256 + threadIdx.x;
  if (i < n) p[i] = 0ull;
}

// ---------------- layer-0 xg GEMM with fused embedding gather (K=150, f32) ----------------
__global__ void __launch_bounds__(256) kgemm0(
    const int* __restrict__ xma, const int* __restrict__ xcpc, const int* __restrict__ xr,
    const float* __restrict__ em, const float* __restrict__ ec, const float* __restrict__ er,
    const float* __restrict__ W, const float* __restrict__ b1, const float* __restrict__ b2,
    float* __restrict__ XG)
{
  __shared__ float xs[8*152];
  const int t0 = blockIdx.x*8;
  const int tid = threadIdx.x;
  for (int idx = tid; idx < 8*150; idx += 256){
    int tt = idx / 150, k = idx - tt*150;
    int t = t0 + tt;
    float v;
    if (k < 50)       v = em[(size_t)xma[t]*50 + k];
    else if (k < 100) v = ec[(size_t)xcpc[t]*50 + (k-50)];
    else              v = er[(size_t)xr[t]*50 + (k-100)];
    xs[tt*152 + k] = v;
  }
  __syncthreads();
  int r = blockIdx.y*256 + tid;
  if (r >= G4) return;
  float acc[8];
  #pragma unroll
  for (int i=0;i<8;i++) acc[i]=0.f;
  const float2* wr = (const float2*)(W + (size_t)r*150);
  for (int k2=0;k2<75;k2++){
    float2 w = wr[k2];
    int k = 2*k2;
    #pragma unroll
    for (int tt=0;tt<8;tt++)
      acc[tt] += w.x*xs[tt*152+k] + w.y*xs[tt*152+k+1];
  }
  float bb = b1[r] + b2[r];
  #pragma unroll
  for (int tt=0;tt<8;tt++)
    XG[(size_t)(t0+tt)*G4 + r] = acc[tt] + bb;
}

// ================== fused 2-layer LSTM scan, single-XCD cluster ==================
// 2048 WGs launched. Gating (ctl zeroed by kzero, agent atomics only):
//   ctl[0]: ticket; taker of 0 is LEADER, publishes its XCC_ID|valid into ctl[1].
//   All WGs spin on ctl[1] (leader publishes promptly -> bounded). WGs whose
//   XCC_ID matches take ctl[2] tickets; first 32 participate, rest exit.
//   => 32 winners all on ONE XCD for any XCC numbering. If XCC_ID were ever
//   non-distinguishing, winners may span XCDs: fast path then times out and the
//   safe ring carries the data -- degraded speed, never a hang.
//   slots 0-15:  role A = layer-0 recurrence (WG w owns h0[25w..25w+25))
//   slots 16-31: role B = FF(Wih1@h0) + layer-1 recurrence (gbuf eliminated;
//                summation order bit-identical to the 3-stage baseline)
// Rings: depth-32 tagged u64 slots. Role A throttles every 16 iters on role-B
// progress (tag t-16 present => B finished iter t-17): max A-lead = 32 = ring
// depth, and every overwritten tag is provably already consumed -> no overrun.
__global__ void __launch_bounds__(448,1) kpipe(
    const float* __restrict__ XG0,
    const float* __restrict__ Whh0, const float* __restrict__ Whh1,
    const float* __restrict__ Wih1, const float* __restrict__ bih1,
    const float* __restrict__ bhh1,
    float* __restrict__ RN,
    unsigned long long* fbufA, unsigned long long* fbufB,
    unsigned long long* hbufA, unsigned long long* hbufB,
    unsigned* ctlw, int T)
{
  __shared__ int s_slot;
  __shared__ float lds_h0[HID];
  __shared__ float lds_h1[HID];
  __shared__ float lds_g[100];
  __shared__ float lds_gf[100];
  __shared__ float lds_hnew[25];

  unsigned xcc;
  asm volatile("s_getreg_b32 %0, hwreg(HW_REG_XCC_ID)" : "=s"(xcc));
  if (threadIdx.x == 0){
    int sl = -1;
    unsigned tk = atomicAdd(ctlw + 0, 1u);
    if (tk == 0u)
      __hip_atomic_store(ctlw + 1, (xcc & 0xffu) | 0x100u,
                         __ATOMIC_RELAXED, __HIP_MEMORY_SCOPE_AGENT);
    unsigned ld;
    do { ld = __hip_atomic_load(ctlw + 1, __ATOMIC_RELAXED, __HIP_MEMORY_SCOPE_AGENT); }
    while (!(ld & 0x100u));
    if ((ld & 0xffu) == (xcc & 0xffu)){
      unsigned t2 = atomicAdd(ctlw + 2, 1u);
      if (t2 < 32u) sl = (int)t2;
    }
    s_slot = sl;
  }
  __syncthreads();
  const int slot = s_slot;
  if (slot < 0) return;

  const int tid = threadIdx.x;
  const int row_local = tid >> 2;        // 0..111 (100 used)
  const int part = tid & 3;              // k-slice of 100
  const bool mat = (tid < 400);
  const bool ew  = (tid < 25);

  if (slot < 16){
    // ---------- role A: layer-0 recurrence (baseline-identical math) ----------
    const int w = slot;
    float wreg[100];
    if (mat){
      int gate = row_local/25, jj = row_local%25;
      int row = gate*400 + w*25 + jj;
      const float4* wr = (const float4*)(Whh0 + (size_t)row*HID) + part*25;
      #pragma unroll
      for (int i=0;i<25;i++){
        float4 v = wr[i];
        wreg[4*i]=v.x; wreg[4*i+1]=v.y; wreg[4*i+2]=v.z; wreg[4*i+3]=v.w;
      }
    }
    const int j = w*25 + tid;
    float c = 0.f;
    for (int t=0; t<T; t++){
      float xgi=0.f, xgf=0.f, xgg=0.f, xgo=0.f;
      if (ew){
        const float* xrw = XG0 + (size_t)t*G4;
        xgi = xrw[j]; xgf = xrw[HID+j]; xgg = xrw[2*HID+j]; xgo = xrw[3*HID+j];
      }
      if (mat){
        float hv = 0.f;
        if (t > 0){
          if (tid >= w*25 && tid < w*25+25){
            hv = lds_hnew[tid - w*25];
          } else {
            int off = (t & (RING-1))*HID + tid;
            hv = poll_dual(fbufA + off, hbufA + off, (unsigned)t);
          }
        }
        lds_h0[tid] = hv;
      }
      __syncthreads();
      float sum = 0.f;
      if (mat){
        const float4* hp = (const float4*)(lds_h0 + part*100);
        #pragma unroll
        for (int i=0;i<25;i++){
          float4 h4 = hp[i];
          sum += wreg[4*i]*h4.x + wreg[4*i+1]*h4.y + wreg[4*i+2]*h4.z + wreg[4*i+3]*h4.w;
        }
      }
      sum += __shfl_xor(sum, 1);
      sum += __shfl_xor(sum, 2);
      if (mat && part==0) lds_g[row_local] = sum;
      __syncthreads();
      if (ew){
        float gi = xgi + lds_g[tid];
        float gf = xgf + lds_g[25+tid];
        float gg = xgg + lds_g[50+tid];
        float go = xgo + lds_g[75+tid];
        float si = fsig(gi), sf = fsig(gf), so = fsig(go), tg = ftanh(gg);
        c = sf*c + si*tg;
        float h = so*ftanh(c);
        lds_hnew[tid] = h;
        // throttle: every 16 iters confirm role B finished iter t-17
        if (t >= 32 && (t & 15) == 0 && tid < 16){
          int off = ((t-16) & (RING-1))*HID + tid*25;
          (void)poll_dual(fbufB + off, hbufB + off, (unsigned)(t-16));
        }
        int off = ((t+1) & (RING-1))*HID + j;
        publish_dual(fbufA + off, hbufA + off, (unsigned)(t+1), h);
      }
      __syncthreads();
    }
  } else {
    // ---------- role B: FF (Wih1 @ h0) + layer-1 recurrence, writes RN ----------
    const int l = slot - 16;
    float wf[100], wh[100];
    float bias = 0.f;
    if (mat){
      int gate = row_local/25, jj = row_local%25;
      int grow = gate*400 + l*25 + jj;
      const float4* wr1 = (const float4*)(Wih1 + (size_t)grow*HID) + part*25;
      const float4* wr2 = (const float4*)(Whh1 + (size_t)grow*HID) + part*25;
      #pragma unroll
      for (int i=0;i<25;i++){
        float4 a = wr1[i]; wf[4*i]=a.x; wf[4*i+1]=a.y; wf[4*i+2]=a.z; wf[4*i+3]=a.w;
        float4 b = wr2[i]; wh[4*i]=b.x; wh[4*i+1]=b.y; wh[4*i+2]=b.z; wh[4*i+3]=b.w;
      }
      if (part==0) bias = bih1[grow] + bhh1[grow];
    }
    const int j = l*25 + tid;
    float c = 0.f;
    for (int t=0; t<T; t++){
      if (mat){
        float h1v = 0.f;
        const bool own = (tid >= l*25 && tid < l*25+25);
        // self-loop value first (the fresh one), then h0 (published earlier)
        if (t > 0 && !own){
          int offb = (t & (RING-1))*HID + tid;
          h1v = poll_dual(fbufB + offb, hbufB + offb, (unsigned)t);
        } else if (t > 0){
          h1v = lds_hnew[tid - l*25];
        }
        int offa = ((t+1) & (RING-1))*HID + tid;
        lds_h0[tid] = poll_dual(fbufA + offa, hbufA + offa, (unsigned)(t+1));
        lds_h1[tid] = h1v;
      }
      __syncthreads();
      float sumf = 0.f, sumh = 0.f;
      if (mat){
        const float4* hp0 = (const float4*)(lds_h0 + part*100);
        const float4* hp1 = (const float4*)(lds_h1 + part*100);
        #pragma unroll
        for (int i=0;i<25;i++){
          float4 a = hp0[i];
          sumf += wf[4*i]*a.x + wf[4*i+1]*a.y + wf[4*i+2]*a.z + wf[4*i+3]*a.w;
          float4 b = hp1[i];
          sumh += wh[4*i]*b.x + wh[4*i+1]*b.y + wh[4*i+2]*b.z + wh[4*i+3]*b.w;
        }
      }
      sumf += __shfl_xor(sumf, 1);
      sumf += __shfl_xor(sumf, 2);
      sumh += __shfl_xor(sumh, 1);
      sumh += __shfl_xor(sumh, 2);
      if (mat && part==0){ lds_gf[row_local] = sumf + bias; lds_g[row_local] = sumh; }
      __syncthreads();
      if (ew){
        float gi = lds_gf[tid]    + lds_g[tid];
        float gf = lds_gf[25+tid] + lds_g[25+tid];
        float gg = lds_gf[50+tid] + lds_g[50+tid];
        float go = lds_gf[75+tid] + lds_g[75+tid];
        float si = fsig(gi), sfo = fsig(gf), so = fsig(go), tg = ftanh(gg);
        c = sfo*c + si*tg;
        float h = so*ftanh(c);
        lds_hnew[tid] = h;
        int off = ((t+1) & (RING-1))*HID + j;
        publish_dual(fbufB + off, hbufB + off, (unsigned)(t+1), h);
        RN[(size_t)t*HID + j] = h;
      }
      __syncthreads();
    }
  }
}

// ---------------- rtoken = RN @ fcW.T + fcb  (f32) ----------------
__global__ void __launch_bounds__(256) krtoken(
    const float* __restrict__ RN, const float* __restrict__ fcW,
    const float* __restrict__ fcb, float* __restrict__ out)
{
  __shared__ float xs[8*400];
  const int t0 = blockIdx.x*8;
  const int tid = threadIdx.x;
  for (int idx = tid; idx < 8*400; idx += 256)
    xs[idx] = RN[(size_t)t0*400 + idx];
  __syncthreads();
  if (tid >= 150) return;
  float acc[8];
  #pragma unroll
  for (int i=0;i<8;i++) acc[i]=0.f;
  const float4* wr = (const float4*)(fcW + (size_t)tid*400);
  for (int k4=0;k4<100;k4++){
    float4 w = wr[k4];
    #pragma unroll
    for (int tt=0;tt<8;tt++){
      const float4 x4 = *(const float4*)(xs + tt*400 + 4*k4);
      acc[tt] += w.x*x4.x + w.y*x4.y + w.z*x4.z + w.w*x4.w;
    }
  }
  float bb = fcb[tid];
  #pragma unroll
  for (int tt=0;tt<8;tt++)
    out[(size_t)(t0+tt)*150 + tid] = acc[tt] + bb;
}

// ---------------- per-t context scalar: v[t] = softmax0(actW@rnn+actb) * sigmoid(D@rnn) ----
__global__ void kfinal(const float* __restrict__ RN, const float* __restrict__ actW,
                       const float* __restrict__ actb, const float* __restrict__ Dp,
                       float* __restrict__ vbuf)
{
  int t = blockIdx.x, l = threadIdx.x;
  const float* r = RN + (size_t)t*HID;
  float s0=0.f, s1=0.f, s2=0.f, sd=0.f;
  for (int k=l; k<HID; k+=64){
    float rv = r[k];
    s0 += actW[k]*rv;
    s1 += actW[400+k]*rv;
    s2 += actW[800+k]*rv;
    sd += Dp[k]*rv;
  }
  #pragma unroll
  for (int o=1;o<64;o<<=1){
    s0 += __shfl_xor(s0,o); s1 += __shfl_xor(s1,o);
    s2 += __shfl_xor(s2,o); sd += __shfl_xor(sd,o);
  }
  if (l==0){
    s0 += actb[0]; s1 += actb[1]; s2 += actb[2];
    float m = fmaxf(s0, fmaxf(s1, s2));
    float e0 = __expf(s0-m), e1 = __expf(s1-m), e2 = __expf(s2-m);
    float p0 = e0/(e0+e1+e2);
    vbuf[t] = p0 * fsig(sd);
  }
}

// ---------------- context write: zero everything, slot0 = v[t] broadcast (f32) ----------------
// LAST kernel: deterministically overwrites the whole ctx region (which doubled as scratch).
__global__ void kctx(const float* __restrict__ vbuf, uint4* __restrict__ ctx, int n16){
  int i = blockIdx.x*256 + threadIdx.x;
  int stride = gridDim.x*256;
  for (; i<n16; i+=stride){
    int t = i / 3200;
    int p = i - t*3200;
    uint4 z;
    if (p < 100){
      float v = vbuf[t];
      union{float f; uint32_t u;} cv; cv.f = v;
      z.x = z.y = z.z = z.w = cv.u;
    } else {
      z.x = z.y = z.z = z.w = 0u;
    }
    ctx[i] = z;
  }
}

// ---------------- key LSTM (1 step, h0=c0=0 so key_Whh is dead) + fc (f32) ----------------
__global__ void __launch_bounds__(512) kkey(
    const float* __restrict__ RN, const float* __restrict__ Wih,
    const float* __restrict__ bih, const float* __restrict__ bhh,
    const float* __restrict__ fcW, const float* __restrict__ fcb,
    float* __restrict__ out)
{
  __shared__ float rh[HID];
  __shared__ float gk[4*KDIM];
  __shared__ float hk[KDIM];
  int tid = threadIdx.x;
  if (tid < HID) rh[tid] = RN[(size_t)(T_LEN-1)*HID + tid];
  __syncthreads();
  for (int r = tid; r < 4*KDIM; r += 512){
    const float4* wr = (const float4*)(Wih + (size_t)r*HID);
    float acc = 0.f;
    for (int k4=0;k4<100;k4++){
      float4 w = wr[k4];
      const float4 x4 = *(const float4*)(rh + 4*k4);
      acc += w.x*x4.x + w.y*x4.y + w.z*x4.z + w.w*x4.w;
    }
    gk[r] = acc + bih[r] + bhh[r];
  }
  __syncthreads();
  if (tid < KDIM){
    float gi = gk[tid], gg = gk[2*KDIM+tid], go = gk[3*KDIM+tid];
    float cc = fsig(gi)*ftanh(gg);        // c0 = 0 -> forget-gate term vanishes
    hk[tid] = fsig(go)*ftanh(cc);
  }
  __syncthreads();
  if (tid < HID){
    const float4* wr = (const float4*)(fcW + (size_t)tid*KDIM);
    float acc = 0.f;
    for (int k4=0;k4<75;k4++){
      float4 w = wr[k4];
      const float4 x4 = *(const float4*)(hk + 4*k4);
      acc += w.x*x4.x + w.y*x4.y + w.z*x4.z + w.w*x4.w;
    }
    out[tid] = acc + fcb[tid];
  }
}

extern "C" void kernel_launch(void* const* d_in, const int* in_sizes, int n_in,
                              void* d_out, int out_size, void* d_ws, size_t ws_size,
                              hipStream_t stream)
{
  (void)in_sizes; (void)n_in; (void)ws_size;
  const int*   xr   = (const int*)d_in[0];
  const int*   xcpc = (const int*)d_in[1];
  const int*   xma  = (const int*)d_in[2];
  const float* em   = (const float*)d_in[3];
  const float* ec   = (const float*)d_in[4];
  const float* er   = (const float*)d_in[5];
  const float* Wih0 = (const float*)d_in[6];
  const float* Whh0 = (const float*)d_in[7];
  const float* bih0 = (const float*)d_in[8];
  const float* bhh0 = (const float*)d_in[9];
  const float* Wih1 = (const float*)d_in[10];
  const float* Whh1 = (const float*)d_in[11];
  const float* bih1 = (const float*)d_in[12];
  const float* bhh1 = (const float*)d_in[13];
  const float* fcW  = (const float*)d_in[14];
  const float* fcb  = (const float*)d_in[15];
  const float* actW = (const float*)d_in[16];
  const float* actb = (const float*)d_in[17];
  const float* Dp   = (const float*)d_in[18];
  const float* kWih = (const float*)d_in[19];
  /* d_in[20] key_Whh unused: h0 = 0 for the single key step */
  const float* kbih = (const float*)d_in[21];
  const float* kbhh = (const float*)d_in[22];
  const float* kfcW = (const float*)d_in[23];
  const float* kfcb = (const float*)d_in[24];

  // ---- vbuf stays in ws (kctx both reads vbuf and rewrites the ctx region) ----
  float* vbuf = (float*)d_ws;                           // 16 KB

  // ---- large scratch + handshake bufs in TAIL of d_out's ctx region (kctx rewrites last) ----
  float* out = (float*)d_out;
  char*  ob  = (char*)d_out;
  size_t total = (size_t)out_size * 4;                  // 212,174,400 bytes
  float* XG0 = (float*)(ob + total - 26214400);         // 4096*1600 f32
  float* RN  = (float*)(ob + total - 32768000);         // 4096*400 f32
  char*  ctl = ob + total - 32768000 - 524288;          // control block (512 KB reserve)
  // layout: [0..4096) ctl words; then fbufA, fbufB, hbufA, hbufB (102,400 B each).
  // kzero wipes all of it before kpipe each run -> no poison dependence.
  unsigned*           ctlw  = (unsigned*)(ctl);
  unsigned long long* fbufA = (unsigned long long*)(ctl + 4096);
  unsigned long long* fbufB = (unsigned long long*)(ctl + 4096 + 102400);
  unsigned long long* hbufA = (unsigned long long*)(ctl + 4096 + 2*102400);
  unsigned long long* hbufB = (unsigned long long*)(ctl + 4096 + 3*102400);
  int nz = (4096 + 4*102400) / 8;                       // 51,712 u64 words

  float* rtok = out;                 // 4096*150
  float* ktok = out + 614400;        // 400
  uint4* ctxp = (uint4*)(ob + 614800u*4u);              // ctx region, 209,715,200 B
  int n16 = (int)((total - 614800u*4u) >> 4);           // 13,107,200

  dim3 gg(T_LEN/8, 7);
  kzero<<<(nz+255)/256,256,0,stream>>>((unsigned long long*)ctl, nz);
  kgemm0<<<gg,256,0,stream>>>(xma, xcpc, xr, em, ec, er, Wih0, bih0, bhh0, XG0);
  kpipe<<<2048,448,0,stream>>>(XG0, Whh0, Whh1, Wih1, bih1, bhh1, RN,
                               fbufA, fbufB, hbufA, hbufB, ctlw, T_LEN);
  krtoken<<<T_LEN/8,256,0,stream>>>(RN, fcW, fcb, rtok);
  kkey<<<1,512,0,stream>>>(RN, kWih, kbih, kbhh, kfcW, kfcb, ktok);
  kfinal<<<T_LEN,64,0,stream>>>(RN, actW, actb, Dp, vbuf);
  kctx<<<2048,256,0,stream>>>(vbuf, ctxp, n16);
}

// Round 6
// 17340.240 us; speedup vs baseline: 1.1927x; 1.1927x over previous
//
#include <hip/hip_runtime.h>
#include <stdint.h>

#define T_LEN 4096
#define HID   400
#define G4    1600
#define KDIM  300
#define RING  32

__device__ __forceinline__ float fsig(float x){ return 1.f/(1.f + __expf(-x)); }
__device__ __forceinline__ float ftanh(float x){ float e = __expf(2.f*x); return 1.f - 2.f/(e+1.f); }

// ---- hang-proof dual-path handshake primitives ----
// Fast path: publisher = plain volatile store (write-through L1 -> local XCD L2;
// PROVEN visible-in-L2 by round 5's FETCH collapse). Consumer = sc0 load
// (GLC-analog: bypass L1, read local L2). Pure loads: no atomic-unit
// serialization, no line dirtying. Valid when producer+consumer share an XCD
// (runtime-gated below).
// Safe path: agent-scope atomics (round-2/5-proven). Published LAZILY (one
// iteration late + final flush) so its ~900cy ack never sits on a barrier.
// Every poll: bounded fast spin (16), then unbounded safe spin -> cannot hang.
__device__ __forceinline__ unsigned long long fast_load(const unsigned long long* p){
  unsigned long long v;
  asm volatile("global_load_dwordx2 %0, %1, off sc0\n"
               "s_waitcnt vmcnt(0)"
               : "=v"(v) : "v"(p) : "memory");
  return v;
}
__device__ __forceinline__ void st_fast(unsigned long long* p, unsigned long long pk){
  *(volatile unsigned long long*)p = pk;   // write-through -> local XCD L2
}
__device__ __forceinline__ float poll_dual(const unsigned long long* fast,
                                           const unsigned long long* safe, unsigned tag){
  for (int k = 0; k < 16; ++k){
    unsigned long long x = fast_load(fast);
    if ((unsigned)(x >> 32) == tag){
      union{unsigned u; float f;} c; c.u = (unsigned)x; return c.f;
    }
  }
  unsigned long long x;
  do { x = __hip_atomic_load(safe, __ATOMIC_RELAXED, __HIP_MEMORY_SCOPE_AGENT); }
  while ((unsigned)(x >> 32) != tag);
  union{unsigned u; float f;} c; c.u = (unsigned)x; return c.f;
}

// LDS-only barrier: order LDS traffic (lgkmcnt) but do NOT drain vmcnt --
// publish-store acks and XG0 prefetch latency stay off the barrier path.
// All cross-iteration LDS reuse in kpipe is lgkm-counted, so this is safe.
#define BAR() asm volatile("s_waitcnt lgkmcnt(0)\n\ts_barrier" ::: "memory")

// ---------------- control-block zeroing (ctl words + both ring pairs) ----------------
__global__ void kzero(unsigned long long* __restrict__ p, int n){
  int i = blockIdx.x*256 + threadIdx.x;
  if (i < n) p[i] = 0ull;
}

// ---------------- layer-0 xg GEMM with fused embedding gather (K=150, f32) ----------------
__global__ void __launch_bounds__(256) kgemm0(
    const int* __restrict__ xma, const int* __restrict__ xcpc, const int* __restrict__ xr,
    const float* __restrict__ em, const float* __restrict__ ec, const float* __restrict__ er,
    const float* __restrict__ W, const float* __restrict__ b1, const float* __restrict__ b2,
    float* __restrict__ XG)
{
  __shared__ float xs[8*152];
  const int t0 = blockIdx.x*8;
  const int tid = threadIdx.x;
  for (int idx = tid; idx < 8*150; idx += 256){
    int tt = idx / 150, k = idx - tt*150;
    int t = t0 + tt;
    float v;
    if (k < 50)       v = em[(size_t)xma[t]*50 + k];
    else if (k < 100) v = ec[(size_t)xcpc[t]*50 + (k-50)];
    else              v = er[(size_t)xr[t]*50 + (k-100)];
    xs[tt*152 + k] = v;
  }
  __syncthreads();
  int r = blockIdx.y*256 + tid;
  if (r >= G4) return;
  float acc[8];
  #pragma unroll
  for (int i=0;i<8;i++) acc[i]=0.f;
  const float2* wr = (const float2*)(W + (size_t)r*150);
  for (int k2=0;k2<75;k2++){
    float2 w = wr[k2];
    int k = 2*k2;
    #pragma unroll
    for (int tt=0;tt<8;tt++)
      acc[tt] += w.x*xs[tt*152+k] + w.y*xs[tt*152+k+1];
  }
  float bb = b1[r] + b2[r];
  #pragma unroll
  for (int tt=0;tt<8;tt++)
    XG[(size_t)(t0+tt)*G4 + r] = acc[tt] + bb;
}

// ================== fused 2-layer LSTM scan, single-XCD cluster ==================
// 2048 WGs launched. Leader-elected XCD gating (round-5-proven): ctl[0] ticket
// elects a leader which publishes its XCC_ID into ctl[1]; WGs on the SAME XCD
// take ctl[2] tickets; first 32 participate, rest exit.
//   slots 0-15:  role A = layer-0 recurrence (WG w owns h0[25w..25w+25))
//   slots 16-31: role B = FF(Wih1@h0) + layer-1 recurrence (gbuf eliminated;
//                summation order bit-identical to the 3-stage baseline)
// Rings: depth-32 tagged u64 {tag,f32}. Role A throttles every 16 iters on
// role-B progress (tag t-16 => B finished t-17): A-lead <= 32 = ring depth and
// every overwritten tag is already consumed -> no overrun, no deadlock.
__global__ void __launch_bounds__(448,1) kpipe(
    const float* __restrict__ XG0,
    const float* __restrict__ Whh0, const float* __restrict__ Whh1,
    const float* __restrict__ Wih1, const float* __restrict__ bih1,
    const float* __restrict__ bhh1,
    float* __restrict__ RN,
    unsigned long long* fbufA, unsigned long long* fbufB,
    unsigned long long* hbufA, unsigned long long* hbufB,
    unsigned* ctlw, int T)
{
  __shared__ int s_slot;
  __shared__ float lds_h0[HID];
  __shared__ float lds_h1[HID];
  __shared__ float lds_g[100];
  __shared__ float lds_gf[100];
  __shared__ float lds_hnew[25];

  unsigned xcc;
  asm volatile("s_getreg_b32 %0, hwreg(HW_REG_XCC_ID)" : "=s"(xcc));
  if (threadIdx.x == 0){
    int sl = -1;
    unsigned tk = atomicAdd(ctlw + 0, 1u);
    if (tk == 0u)
      __hip_atomic_store(ctlw + 1, (xcc & 0xffu) | 0x100u,
                         __ATOMIC_RELAXED, __HIP_MEMORY_SCOPE_AGENT);
    unsigned ld;
    do { ld = __hip_atomic_load(ctlw + 1, __ATOMIC_RELAXED, __HIP_MEMORY_SCOPE_AGENT); }
    while (!(ld & 0x100u));
    if ((ld & 0xffu) == (xcc & 0xffu)){
      unsigned t2 = atomicAdd(ctlw + 2, 1u);
      if (t2 < 32u) sl = (int)t2;
    }
    s_slot = sl;
  }
  __syncthreads();
  const int slot = s_slot;
  if (slot < 0) return;

  const int tid = threadIdx.x;
  const int row_local = tid >> 2;        // 0..111 (100 used)
  const int part = tid & 3;              // k-slice of 100
  const bool mat = (tid < 400);
  const bool ew  = (tid < 25);

  if (slot < 16){
    // ---------- role A: layer-0 recurrence (baseline-identical math) ----------
    const int w = slot;
    float wreg[100];
    if (mat){
      int gate = row_local/25, jj = row_local%25;
      int row = gate*400 + w*25 + jj;
      const float4* wr = (const float4*)(Whh0 + (size_t)row*HID) + part*25;
      #pragma unroll
      for (int i=0;i<25;i++){
        float4 v = wr[i];
        wreg[4*i]=v.x; wreg[4*i+1]=v.y; wreg[4*i+2]=v.z; wreg[4*i+3]=v.w;
      }
    }
    const int j = w*25 + tid;
    float c = 0.f;
    unsigned long long pend = 0ull;       // lazy safe-ring payload (tag t)
    for (int t=0; t<T; t++){
      float xgi=0.f, xgf=0.f, xgg=0.f, xgo=0.f;
      if (ew){
        if (t > 0)   // lazy safe publish of tag t: ack overlaps this whole iter
          __hip_atomic_store(hbufA + (size_t)(t & (RING-1))*HID + j, pend,
                             __ATOMIC_RELAXED, __HIP_MEMORY_SCOPE_AGENT);
        const float* xrw = XG0 + (size_t)t*G4;
        xgi = xrw[j]; xgf = xrw[HID+j]; xgg = xrw[2*HID+j]; xgo = xrw[3*HID+j];
      }
      if (mat){
        float hv = 0.f;
        if (t > 0){
          if (tid >= w*25 && tid < w*25+25){
            hv = lds_hnew[tid - w*25];
          } else {
            int off = (t & (RING-1))*HID + tid;
            hv = poll_dual(fbufA + off, hbufA + off, (unsigned)t);
          }
        }
        lds_h0[tid] = hv;
      }
      BAR();
      float sum = 0.f;
      if (mat){
        const float4* hp = (const float4*)(lds_h0 + part*100);
        #pragma unroll
        for (int i=0;i<25;i++){
          float4 h4 = hp[i];
          sum += wreg[4*i]*h4.x + wreg[4*i+1]*h4.y + wreg[4*i+2]*h4.z + wreg[4*i+3]*h4.w;
        }
      }
      sum += __shfl_xor(sum, 1);
      sum += __shfl_xor(sum, 2);
      if (mat && part==0) lds_g[row_local] = sum;
      BAR();
      if (ew){
        float gi = xgi + lds_g[tid];
        float gf = xgf + lds_g[25+tid];
        float gg = xgg + lds_g[50+tid];
        float go = xgo + lds_g[75+tid];
        float si = fsig(gi), sf = fsig(gf), so = fsig(go), tg = ftanh(gg);
        c = sf*c + si*tg;
        float h = so*ftanh(c);
        lds_hnew[tid] = h;
        // throttle: every 16 iters confirm role B finished iter t-17
        if (t >= 32 && (t & 15) == 0 && tid < 16){
          int off = ((t-16) & (RING-1))*HID + tid*25;
          (void)poll_dual(fbufB + off, hbufB + off, (unsigned)(t-16));
        }
        union{unsigned u; float f;} cv; cv.f = h;
        pend = ((unsigned long long)(unsigned)(t+1) << 32) | (unsigned long long)cv.u;
        st_fast(fbufA + (size_t)((t+1) & (RING-1))*HID + j, pend);
      }
      BAR();
    }
    if (ew)   // flush last safe tag (T) for fallback consumers
      __hip_atomic_store(hbufA + (size_t)(T & (RING-1))*HID + j, pend,
                         __ATOMIC_RELAXED, __HIP_MEMORY_SCOPE_AGENT);
  } else {
    // ---------- role B: FF (Wih1 @ h0) + layer-1 recurrence, writes RN ----------
    const int l = slot - 16;
    float wf[100], wh[100];
    float bias = 0.f;
    if (mat){
      int gate = row_local/25, jj = row_local%25;
      int grow = gate*400 + l*25 + jj;
      const float4* wr1 = (const float4*)(Wih1 + (size_t)grow*HID) + part*25;
      const float4* wr2 = (const float4*)(Whh1 + (size_t)grow*HID) + part*25;
      #pragma unroll
      for (int i=0;i<25;i++){
        float4 a = wr1[i]; wf[4*i]=a.x; wf[4*i+1]=a.y; wf[4*i+2]=a.z; wf[4*i+3]=a.w;
        float4 b = wr2[i]; wh[4*i]=b.x; wh[4*i+1]=b.y; wh[4*i+2]=b.z; wh[4*i+3]=b.w;
      }
      if (part==0) bias = bih1[grow] + bhh1[grow];
    }
    const int j = l*25 + tid;
    float c = 0.f;
    unsigned long long pend = 0ull;
    for (int t=0; t<T; t++){
      if (ew && t > 0)   // lazy safe publish of tag t
        __hip_atomic_store(hbufB + (size_t)(t & (RING-1))*HID + j, pend,
                           __ATOMIC_RELAXED, __HIP_MEMORY_SCOPE_AGENT);
      if (mat){
        float h1v = 0.f;
        const bool own = (tid >= l*25 && tid < l*25+25);
        if (t > 0 && !own){
          int offb = (t & (RING-1))*HID + tid;
          h1v = poll_dual(fbufB + offb, hbufB + offb, (unsigned)t);
        } else if (t > 0){
          h1v = lds_hnew[tid - l*25];
        }
        int offa = ((t+1) & (RING-1))*HID + tid;
        lds_h0[tid] = poll_dual(fbufA + offa, hbufA + offa, (unsigned)(t+1));
        lds_h1[tid] = h1v;
      }
      BAR();
      float sumf = 0.f, sumh = 0.f;
      if (mat){
        const float4* hp0 = (const float4*)(lds_h0 + part*100);
        const float4* hp1 = (const float4*)(lds_h1 + part*100);
        #pragma unroll
        for (int i=0;i<25;i++){
          float4 a = hp0[i];
          sumf += wf[4*i]*a.x + wf[4*i+1]*a.y + wf[4*i+2]*a.z + wf[4*i+3]*a.w;
          float4 b = hp1[i];
          sumh += wh[4*i]*b.x + wh[4*i+1]*b.y + wh[4*i+2]*b.z + wh[4*i+3]*b.w;
        }
      }
      sumf += __shfl_xor(sumf, 1);
      sumf += __shfl_xor(sumf, 2);
      sumh += __shfl_xor(sumh, 1);
      sumh += __shfl_xor(sumh, 2);
      if (mat && part==0){ lds_gf[row_local] = sumf + bias; lds_g[row_local] = sumh; }
      BAR();
      if (ew){
        float gi = lds_gf[tid]    + lds_g[tid];
        float gf = lds_gf[25+tid] + lds_g[25+tid];
        float gg = lds_gf[50+tid] + lds_g[50+tid];
        float go = lds_gf[75+tid] + lds_g[75+tid];
        float si = fsig(gi), sfo = fsig(gf), so = fsig(go), tg = ftanh(gg);
        c = sfo*c + si*tg;
        float h = so*ftanh(c);
        lds_hnew[tid] = h;
        union{unsigned u; float f;} cv; cv.f = h;
        pend = ((unsigned long long)(unsigned)(t+1) << 32) | (unsigned long long)cv.u;
        st_fast(fbufB + (size_t)((t+1) & (RING-1))*HID + j, pend);
        RN[(size_t)t*HID + j] = h;
      }
      BAR();
    }
    if (ew)
      __hip_atomic_store(hbufB + (size_t)(T & (RING-1))*HID + j, pend,
                         __ATOMIC_RELAXED, __HIP_MEMORY_SCOPE_AGENT);
  }
}

// ---------------- rtoken = RN @ fcW.T + fcb  (f32) ----------------
__global__ void __launch_bounds__(256) krtoken(
    const float* __restrict__ RN, const float* __restrict__ fcW,
    const float* __restrict__ fcb, float* __restrict__ out)
{
  __shared__ float xs[8*400];
  const int t0 = blockIdx.x*8;
  const int tid = threadIdx.x;
  for (int idx = tid; idx < 8*400; idx += 256)
    xs[idx] = RN[(size_t)t0*400 + idx];
  __syncthreads();
  if (tid >= 150) return;
  float acc[8];
  #pragma unroll
  for (int i=0;i<8;i++) acc[i]=0.f;
  const float4* wr = (const float4*)(fcW + (size_t)tid*400);
  for (int k4=0;k4<100;k4++){
    float4 w = wr[k4];
    #pragma unroll
    for (int tt=0;tt<8;tt++){
      const float4 x4 = *(const float4*)(xs + tt*400 + 4*k4);
      acc[tt] += w.x*x4.x + w.y*x4.y + w.z*x4.z + w.w*x4.w;
    }
  }
  float bb = fcb[tid];
  #pragma unroll
  for (int tt=0;tt<8;tt++)
    out[(size_t)(t0+tt)*150 + tid] = acc[tt] + bb;
}

// ---------------- per-t context scalar: v[t] = softmax0(actW@rnn+actb) * sigmoid(D@rnn) ----
__global__ void kfinal(const float* __restrict__ RN, const float* __restrict__ actW,
                       const float* __restrict__ actb, const float* __restrict__ Dp,
                       float* __restrict__ vbuf)
{
  int t = blockIdx.x, l = threadIdx.x;
  const float* r = RN + (size_t)t*HID;
  float s0=0.f, s1=0.f, s2=0.f, sd=0.f;
  for (int k=l; k<HID; k+=64){
    float rv = r[k];
    s0 += actW[k]*rv;
    s1 += actW[400+k]*rv;
    s2 += actW[800+k]*rv;
    sd += Dp[k]*rv;
  }
  #pragma unroll
  for (int o=1;o<64;o<<=1){
    s0 += __shfl_xor(s0,o); s1 += __shfl_xor(s1,o);
    s2 += __shfl_xor(s2,o); sd += __shfl_xor(sd,o);
  }
  if (l==0){
    s0 += actb[0]; s1 += actb[1]; s2 += actb[2];
    float m = fmaxf(s0, fmaxf(s1, s2));
    float e0 = __expf(s0-m), e1 = __expf(s1-m), e2 = __expf(s2-m);
    float p0 = e0/(e0+e1+e2);
    vbuf[t] = p0 * fsig(sd);
  }
}

// ---------------- context write: zero everything, slot0 = v[t] broadcast (f32) ----------------
// LAST kernel: deterministically overwrites the whole ctx region (which doubled as scratch).
__global__ void kctx(const float* __restrict__ vbuf, uint4* __restrict__ ctx, int n16){
  int i = blockIdx.x*256 + threadIdx.x;
  int stride = gridDim.x*256;
  for (; i<n16; i+=stride){
    int t = i / 3200;
    int p = i - t*3200;
    uint4 z;
    if (p < 100){
      float v = vbuf[t];
      union{float f; uint32_t u;} cv; cv.f = v;
      z.x = z.y = z.z = z.w = cv.u;
    } else {
      z.x = z.y = z.z = z.w = 0u;
    }
    ctx[i] = z;
  }
}

// ---------------- key LSTM (1 step, h0=c0=0 so key_Whh is dead) + fc (f32) ----------------
__global__ void __launch_bounds__(512) kkey(
    const float* __restrict__ RN, const float* __restrict__ Wih,
    const float* __restrict__ bih, const float* __restrict__ bhh,
    const float* __restrict__ fcW, const float* __restrict__ fcb,
    float* __restrict__ out)
{
  __shared__ float rh[HID];
  __shared__ float gk[4*KDIM];
  __shared__ float hk[KDIM];
  int tid = threadIdx.x;
  if (tid < HID) rh[tid] = RN[(size_t)(T_LEN-1)*HID + tid];
  __syncthreads();
  for (int r = tid; r < 4*KDIM; r += 512){
    const float4* wr = (const float4*)(Wih + (size_t)r*HID);
    float acc = 0.f;
    for (int k4=0;k4<100;k4++){
      float4 w = wr[k4];
      const float4 x4 = *(const float4*)(rh + 4*k4);
      acc += w.x*x4.x + w.y*x4.y + w.z*x4.z + w.w*x4.w;
    }
    gk[r] = acc + bih[r] + bhh[r];
  }
  __syncthreads();
  if (tid < KDIM){
    float gi = gk[tid], gg = gk[2*KDIM+tid], go = gk[3*KDIM+tid];
    float cc = fsig(gi)*ftanh(gg);        // c0 = 0 -> forget-gate term vanishes
    hk[tid] = fsig(go)*ftanh(cc);
  }
  __syncthreads();
  if (tid < HID){
    const float4* wr = (const float4*)(fcW + (size_t)tid*KDIM);
    float acc = 0.f;
    for (int k4=0;k4<75;k4++){
      float4 w = wr[k4];
      const float4 x4 = *(const float4*)(hk + 4*k4);
      acc += w.x*x4.x + w.y*x4.y + w.z*x4.z + w.w*x4.w;
    }
    out[tid] = acc + fcb[tid];
  }
}

extern "C" void kernel_launch(void* const* d_in, const int* in_sizes, int n_in,
                              void* d_out, int out_size, void* d_ws, size_t ws_size,
                              hipStream_t stream)
{
  (void)in_sizes; (void)n_in; (void)ws_size;
  const int*   xr   = (const int*)d_in[0];
  const int*   xcpc = (const int*)d_in[1];
  const int*   xma  = (const int*)d_in[2];
  const float* em   = (const float*)d_in[3];
  const float* ec   = (const float*)d_in[4];
  const float* er   = (const float*)d_in[5];
  const float* Wih0 = (const float*)d_in[6];
  const float* Whh0 = (const float*)d_in[7];
  const float* bih0 = (const float*)d_in[8];
  const float* bhh0 = (const float*)d_in[9];
  const float* Wih1 = (const float*)d_in[10];
  const float* Whh1 = (const float*)d_in[11];
  const float* bih1 = (const float*)d_in[12];
  const float* bhh1 = (const float*)d_in[13];
  const float* fcW  = (const float*)d_in[14];
  const float* fcb  = (const float*)d_in[15];
  const float* actW = (const float*)d_in[16];
  const float* actb = (const float*)d_in[17];
  const float* Dp   = (const float*)d_in[18];
  const float* kWih = (const float*)d_in[19];
  /* d_in[20] key_Whh unused: h0 = 0 for the single key step */
  const float* kbih = (const float*)d_in[21];
  const float* kbhh = (const float*)d_in[22];
  const float* kfcW = (const float*)d_in[23];
  const float* kfcb = (const float*)d_in[24];

  // ---- vbuf stays in ws (kctx both reads vbuf and rewrites the ctx region) ----
  float* vbuf = (float*)d_ws;                           // 16 KB

  // ---- large scratch + handshake bufs in TAIL of d_out's ctx region (kctx rewrites last) ----
  float* out = (float*)d_out;
  char*  ob  = (char*)d_out;
  size_t total = (size_t)out_size * 4;                  // 212,174,400 bytes
  float* XG0 = (float*)(ob + total - 26214400);         // 4096*1600 f32
  float* RN  = (float*)(ob + total - 32768000);         // 4096*400 f32
  char*  ctl = ob + total - 32768000 - 524288;          // control block (512 KB reserve)
  // layout: [0..4096) ctl words; then fbufA, fbufB, hbufA, hbufB (102,400 B each).
  // kzero wipes all of it before kpipe each run -> no poison dependence.
  unsigned*           ctlw  = (unsigned*)(ctl);
  unsigned long long* fbufA = (unsigned long long*)(ctl + 4096);
  unsigned long long* fbufB = (unsigned long long*)(ctl + 4096 + 102400);
  unsigned long long* hbufA = (unsigned long long*)(ctl + 4096 + 2*102400);
  unsigned long long* hbufB = (unsigned long long*)(ctl + 4096 + 3*102400);
  int nz = (4096 + 4*102400) / 8;                       // 51,712 u64 words

  float* rtok = out;                 // 4096*150
  float* ktok = out + 614400;        // 400
  uint4* ctxp = (uint4*)(ob + 614800u*4u);              // ctx region, 209,715,200 B
  int n16 = (int)((total - 614800u*4u) >> 4);           // 13,107,200

  dim3 gg(T_LEN/8, 7);
  kzero<<<(nz+255)/256,256,0,stream>>>((unsigned long long*)ctl, nz);
  kgemm0<<<gg,256,0,stream>>>(xma, xcpc, xr, em, ec, er, Wih0, bih0, bhh0, XG0);
  kpipe<<<2048,448,0,stream>>>(XG0, Whh0, Whh1, Wih1, bih1, bhh1, RN,
                               fbufA, fbufB, hbufA, hbufB, ctlw, T_LEN);
  krtoken<<<T_LEN/8,256,0,stream>>>(RN, fcW, fcb, rtok);
  kkey<<<1,512,0,stream>>>(RN, kWih, kbih, kbhh, kfcW, kfcb, ktok);
  kfinal<<<T_LEN,64,0,stream>>>(RN, actW, actb, Dp, vbuf);
  kctx<<<2048,256,0,stream>>>(vbuf, ctxp, n16);
}

// Round 7
// 9523.182 us; speedup vs baseline: 2.1717x; 1.8208x over previous
//
#include <hip/hip_runtime.h>
#include <stdint.h>

#define T_LEN 4096
#define HID   400
#define G4    1600
#define KDIM  300
#define RING  32

__device__ __forceinline__ float fsig(float x){ return 1.f/(1.f + __expf(-x)); }
__device__ __forceinline__ float ftanh(float x){ float e = __expf(2.f*x); return 1.f - 2.f/(e+1.f); }

// ---------- intra-XCD (same-L2) handshake ----------
// Publisher: plain volatile store (write-through -> local TCC; PROVEN visible, r5/r6).
// Poll rotation: 12x nt-load (cheap L2 read if nt bypasses L1; tag-validated so a
// stale L1 hit merely fails the check) then 4x workgroup-scope atomic RMW(+0),
// which executes AT the TCC (r5-proven fresh) -> liveness guaranteed.
// Single-writer-XCD invariant: only one XCD's CUs ever touch a given ring, so the
// local TCC always holds/owns the line (or IF has the written-back fresh copy).
__device__ __forceinline__ unsigned long long nt_load(const unsigned long long* p){
  unsigned long long v;
  asm volatile("global_load_dwordx2 %0, %1, off nt\n"
               "s_waitcnt vmcnt(0)"
               : "=v"(v) : "v"(p) : "memory");
  return v;
}
__device__ __forceinline__ float poll_local(unsigned long long* p, unsigned tag){
  for(;;){
    #pragma unroll 1
    for (int k=0;k<12;k++){
      unsigned long long x = nt_load(p);
      if ((unsigned)(x >> 32) == tag){
        union{unsigned u; float f;} c; c.u = (unsigned)x; return c.f;
      }
    }
    #pragma unroll 1
    for (int k=0;k<4;k++){
      unsigned long long x = __hip_atomic_fetch_add(p, 0ull, __ATOMIC_RELAXED,
                                                    __HIP_MEMORY_SCOPE_WORKGROUP);
      if ((unsigned)(x >> 32) == tag){
        union{unsigned u; float f;} c; c.u = (unsigned)x; return c.f;
      }
    }
  }
}
__device__ __forceinline__ void st_local(unsigned long long* p, unsigned tag, float v){
  union{unsigned u; float f;} c; c.f = v;
  *(volatile unsigned long long*)p =
      ((unsigned long long)tag << 32) | (unsigned long long)c.u;
}

// LDS-only barrier (r6-proven): order LDS, don't drain vmcnt (keeps store acks
// and prefetch latency off the barrier path; every vmem consumer is waited by
// compiler-inserted targeted s_waitcnt on its result).
#define BAR() asm volatile("s_waitcnt lgkmcnt(0)\n\ts_barrier" ::: "memory")

// ---------------- control-block zeroing ----------------
__global__ void kzero(unsigned long long* __restrict__ p, int n){
  int i = blockIdx.x*256 + threadIdx.x;
  if (i < n) p[i] = 0ull;
}

// ---------------- layer-0 xg GEMM with fused embedding gather ----------------
__global__ void __launch_bounds__(256) kgemm0(
    const int* __restrict__ xma, const int* __restrict__ xcpc, const int* __restrict__ xr,
    const float* __restrict__ em, const float* __restrict__ ec, const float* __restrict__ er,
    const float* __restrict__ W, const float* __restrict__ b1, const float* __restrict__ b2,
    float* __restrict__ XG)
{
  __shared__ float xs[8*152];
  const int t0 = blockIdx.x*8;
  const int tid = threadIdx.x;
  for (int idx = tid; idx < 8*150; idx += 256){
    int tt = idx / 150, k = idx - tt*150;
    int t = t0 + tt;
    float v;
    if (k < 50)       v = em[(size_t)xma[t]*50 + k];
    else if (k < 100) v = ec[(size_t)xcpc[t]*50 + (k-50)];
    else              v = er[(size_t)xr[t]*50 + (k-100)];
    xs[tt*152 + k] = v;
  }
  __syncthreads();
  int r = blockIdx.y*256 + tid;
  if (r >= G4) return;
  float acc[8];
  #pragma unroll
  for (int i=0;i<8;i++) acc[i]=0.f;
  const float2* wr = (const float2*)(W + (size_t)r*150);
  for (int k2=0;k2<75;k2++){
    float2 w = wr[k2];
    int k = 2*k2;
    #pragma unroll
    for (int tt=0;tt<8;tt++)
      acc[tt] += w.x*xs[tt*152+k] + w.y*xs[tt*152+k+1];
  }
  float bb = b1[r] + b2[r];
  #pragma unroll
  for (int tt=0;tt<8;tt++)
    XG[(size_t)(t0+tt)*G4 + r] = acc[tt] + bb;
}

// ================== fused 2-layer LSTM scan: 3-stage pipeline, 2 XCDs ==================
// 2048 WGs launched; 100KB LDS pad forces 1 WG/CU, so winners occupy DISTINCT CUs.
// Election (agent atomics, r5/r6-proven): ctl[0] ticket -> taker-0 publishes alpha
// XCC into ctl[1]. alpha WGs take ctl[2]: 0-15 = A (layer-0), 16-31 = F (FF).
// Non-alpha WGs CAS ctl[4] to define beta (no spin: own CAS makes it valid);
// beta WGs take ctl[5]: 0-15 = B (layer-1). Everyone else exits.
//   A,F on alpha: hA ring is XCD-local (fast plane).  B on beta: hB local.
//   F->B g ring + B->A progress word: cross-XCD -> agent-scope (baseline plane),
//   both consumed in pipeline shadow (F runs ~2 iters ahead of B; A throttled
//   every 8 iters to lead <= 16 < RING=32 -> overrun-free, audited).
// Per iter, 3 barriers (baseline-proven shape). Lane roles: mat=0-399 (matvec,
// local poll), gpoll/gpub=400-499 (agent g ops, in matvec shadow), ew=448-472
// (cell update; also wave-7 so its vmcnt waits never stall mat polls).
__global__ void __launch_bounds__(512,1) kpipe(
    const float* __restrict__ XG0,
    const float* __restrict__ Whh0, const float* __restrict__ Whh1,
    const float* __restrict__ Wih1, const float* __restrict__ bih1,
    const float* __restrict__ bhh1,
    float* __restrict__ RN,
    unsigned long long* hA, unsigned long long* hB, unsigned long long* gb,
    unsigned* ctlw, int T)
{
  __shared__ int s_role, s_sub;
  __shared__ float lds_h[HID];
  __shared__ float lds_g[100];
  __shared__ float lds_xg[100];
  __shared__ float lds_hnew[25];
  __shared__ float lds_pad[25600];   // 100 KB: forces 1 WG/CU -> distinct-CU winners

  unsigned xcc;
  asm volatile("s_getreg_b32 %0, hwreg(HW_REG_XCC_ID)" : "=s"(xcc));
  if (threadIdx.x == 0){
    int role = -1, sub = 0;
    unsigned tk = atomicAdd(ctlw + 0, 1u);
    if (tk == 0u)
      __hip_atomic_store(ctlw + 1, (xcc & 0xffu) | 0x100u,
                         __ATOMIC_RELAXED, __HIP_MEMORY_SCOPE_AGENT);
    unsigned aw;
    do { aw = __hip_atomic_load(ctlw + 1, __ATOMIC_RELAXED, __HIP_MEMORY_SCOPE_AGENT); }
    while (!(aw & 0x100u));
    if ((aw & 0xffu) == (xcc & 0xffu)){
      unsigned t2 = atomicAdd(ctlw + 2, 1u);
      if (t2 < 16u){ role = 0; sub = (int)t2; }
      else if (t2 < 32u){ role = 1; sub = (int)t2 - 16; }
    } else {
      unsigned exp0 = 0u;
      __hip_atomic_compare_exchange_strong(ctlw + 4, &exp0, (xcc & 0xffu) | 0x100u,
          __ATOMIC_RELAXED, __ATOMIC_RELAXED, __HIP_MEMORY_SCOPE_AGENT);
      unsigned bw = __hip_atomic_load(ctlw + 4, __ATOMIC_RELAXED, __HIP_MEMORY_SCOPE_AGENT);
      if ((bw & 0xffu) == (xcc & 0xffu)){
        unsigned t3 = atomicAdd(ctlw + 5, 1u);
        if (t3 < 16u){ role = 2; sub = (int)t3; }
      }
    }
    s_role = role; s_sub = sub;
  }
  __syncthreads();
  const int role = s_role;
  const int sub  = s_sub;
  if (role == -7) lds_pad[threadIdx.x] = 1.f;   // opaque keep-alive for the pad
  if (role < 0) return;

  const int tid = threadIdx.x;
  const int row_local = tid >> 2;       // 0..99 used
  const int part = tid & 3;
  const bool mat = (tid < 400);
  const bool gp  = (tid >= 400 && tid < 500);   // g-poll (B) / g-publish (F)
  const bool ew  = (tid >= 448 && tid < 473);   // cell-update lanes (wave 7)
  const int  e   = tid - 448;

  if (role == 0){
    // ================= stage A: layer-0 recurrence (XCD alpha) =================
    const int w = sub;
    float wreg[100];
    if (mat){
      int gate = row_local/25, jj = row_local%25;
      int row = gate*400 + w*25 + jj;
      const float4* wr = (const float4*)(Whh0 + (size_t)row*HID) + part*25;
      #pragma unroll
      for (int i=0;i<25;i++){
        float4 v = wr[i];
        wreg[4*i]=v.x; wreg[4*i+1]=v.y; wreg[4*i+2]=v.z; wreg[4*i+3]=v.w;
      }
    }
    const int j = w*25 + e;
    float c = 0.f;
    for (int t=0; t<T; t++){
      if (mat){
        float hv = 0.f;
        if (t > 0){
          if (tid >= w*25 && tid < w*25+25) hv = lds_hnew[tid - w*25];
          else hv = poll_local(hA + (size_t)(t & (RING-1))*HID + tid, (unsigned)t);
        }
        lds_h[tid] = hv;
      }
      BAR();
      float sum = 0.f;
      float xgi=0.f, xgf=0.f, xgg=0.f, xgo=0.f;
      if (mat){
        const float4* hp = (const float4*)(lds_h + part*100);
        #pragma unroll
        for (int i=0;i<25;i++){
          float4 h4 = hp[i];
          sum += wreg[4*i]*h4.x + wreg[4*i+1]*h4.y + wreg[4*i+2]*h4.z + wreg[4*i+3]*h4.w;
        }
      } else {
        if (ew){
          const float* xrw = XG0 + (size_t)t*G4;
          xgi = xrw[j]; xgf = xrw[HID+j]; xgg = xrw[2*HID+j]; xgo = xrw[3*HID+j];
        }
        // throttle: every 8 iters bound A's lead over B to <=16 (< RING)
        if (tid == 448 && t >= 16 && (t & 7) == 0){
          unsigned want = (unsigned)(t - 8);
          unsigned v;
          do { v = __hip_atomic_load(ctlw + 6, __ATOMIC_RELAXED, __HIP_MEMORY_SCOPE_AGENT); }
          while ((int)(v - want) < 0);
        }
      }
      sum += __shfl_xor(sum, 1);
      sum += __shfl_xor(sum, 2);
      if (mat && part==0) lds_g[row_local] = sum;
      BAR();
      if (ew){
        float gi = xgi + lds_g[e];
        float gf = xgf + lds_g[25+e];
        float gg = xgg + lds_g[50+e];
        float go = xgo + lds_g[75+e];
        float si = fsig(gi), sf = fsig(gf), so = fsig(go), tg = ftanh(gg);
        c = sf*c + si*tg;
        float h = so*ftanh(c);
        lds_hnew[e] = h;
        st_local(hA + (size_t)((t+1) & (RING-1))*HID + j, (unsigned)(t+1), h);
      }
      BAR();
    }
  } else if (role == 1){
    // ================= stage F: xg1 = Wih1 @ h0 + biases (XCD alpha) =================
    const int f = sub;
    float wreg[100];
    float bias = 0.f;
    int grow = 0;
    if (mat){
      int gate = row_local/25, jj = row_local%25;
      int row = gate*400 + f*25 + jj;
      const float4* wr = (const float4*)(Wih1 + (size_t)row*HID) + part*25;
      #pragma unroll
      for (int i=0;i<25;i++){
        float4 v = wr[i];
        wreg[4*i]=v.x; wreg[4*i+1]=v.y; wreg[4*i+2]=v.z; wreg[4*i+3]=v.w;
      }
    }
    if (gp){
      int p = tid - 400;
      int gate = p/25, jj = p%25;
      grow = gate*400 + f*25 + jj;
      bias = bih1[grow] + bhh1[grow];
    }
    for (int t=0; t<T; t++){
      if (mat)
        lds_h[tid] = poll_local(hA + (size_t)((t+1) & (RING-1))*HID + tid, (unsigned)(t+1));
      BAR();
      float sum = 0.f;
      if (mat){
        const float4* hp = (const float4*)(lds_h + part*100);
        #pragma unroll
        for (int i=0;i<25;i++){
          float4 h4 = hp[i];
          sum += wreg[4*i]*h4.x + wreg[4*i+1]*h4.y + wreg[4*i+2]*h4.z + wreg[4*i+3]*h4.w;
        }
      }
      sum += __shfl_xor(sum, 1);
      sum += __shfl_xor(sum, 2);
      if (mat && part==0) lds_g[row_local] = sum;
      BAR();
      if (gp){
        int p = tid - 400;
        union{unsigned u; float f;} cv; cv.f = lds_g[p] + bias;
        unsigned long long pk =
            ((unsigned long long)(unsigned)(t+1) << 32) | (unsigned long long)cv.u;
        __hip_atomic_store(gb + (size_t)((t+1) & (RING-1))*G4 + grow, pk,
                           __ATOMIC_RELAXED, __HIP_MEMORY_SCOPE_AGENT);
      }
      BAR();
    }
  } else {
    // ================= stage B: layer-1 recurrence (XCD beta) =================
    const int l = sub;
    float wreg[100];
    int grow = 0;
    if (mat){
      int gate = row_local/25, jj = row_local%25;
      int row = gate*400 + l*25 + jj;
      const float4* wr = (const float4*)(Whh1 + (size_t)row*HID) + part*25;
      #pragma unroll
      for (int i=0;i<25;i++){
        float4 v = wr[i];
        wreg[4*i]=v.x; wreg[4*i+1]=v.y; wreg[4*i+2]=v.z; wreg[4*i+3]=v.w;
      }
    }
    if (gp){
      int p = tid - 400;
      int gate = p/25, jj = p%25;
      grow = gate*400 + l*25 + jj;
    }
    const int j = l*25 + e;
    float c = 0.f;
    for (int t=0; t<T; t++){
      if (mat){
        float hv = 0.f;
        if (t > 0){
          if (tid >= l*25 && tid < l*25+25) hv = lds_hnew[tid - l*25];
          else hv = poll_local(hB + (size_t)(t & (RING-1))*HID + tid, (unsigned)t);
        }
        lds_h[tid] = hv;
      }
      BAR();
      float sum = 0.f;
      if (mat){
        const float4* hp = (const float4*)(lds_h + part*100);
        #pragma unroll
        for (int i=0;i<25;i++){
          float4 h4 = hp[i];
          sum += wreg[4*i]*h4.x + wreg[4*i+1]*h4.y + wreg[4*i+2]*h4.z + wreg[4*i+3]*h4.w;
        }
      } else if (gp){
        // agent poll of F's xg1(t+1) in the matvec shadow (F runs ~2 iters ahead)
        int p = tid - 400;
        const unsigned long long* src = gb + (size_t)((t+1) & (RING-1))*G4 + grow;
        unsigned want = (unsigned)(t+1);
        unsigned long long x;
        do { x = __hip_atomic_load(src, __ATOMIC_RELAXED, __HIP_MEMORY_SCOPE_AGENT); }
        while ((unsigned)(x >> 32) != want);
        union{unsigned u; float f;} cv; cv.u = (unsigned)x;
        lds_xg[p] = cv.f;
      }
      sum += __shfl_xor(sum, 1);
      sum += __shfl_xor(sum, 2);
      if (mat && part==0) lds_g[row_local] = sum;
      BAR();
      if (ew){
        float gi = lds_xg[e]    + lds_g[e];
        float gf = lds_xg[25+e] + lds_g[25+e];
        float gg = lds_xg[50+e] + lds_g[50+e];
        float go = lds_xg[75+e] + lds_g[75+e];
        float si = fsig(gi), sfo = fsig(gf), so = fsig(go), tg = ftanh(gg);
        c = sfo*c + si*tg;
        float h = so*ftanh(c);
        lds_hnew[e] = h;
        st_local(hB + (size_t)((t+1) & (RING-1))*HID + j, (unsigned)(t+1), h);
        RN[(size_t)t*HID + j] = h;
        if (tid == 448 && (t & 7) == 0)
          __hip_atomic_store(ctlw + 6, (unsigned)t,
                             __ATOMIC_RELAXED, __HIP_MEMORY_SCOPE_AGENT);
      }
      BAR();
    }
  }
}

// ---------------- rtoken = RN @ fcW.T + fcb ----------------
__global__ void __launch_bounds__(256) krtoken(
    const float* __restrict__ RN, const float* __restrict__ fcW,
    const float* __restrict__ fcb, float* __restrict__ out)
{
  __shared__ float xs[8*400];
  const int t0 = blockIdx.x*8;
  const int tid = threadIdx.x;
  for (int idx = tid; idx < 8*400; idx += 256)
    xs[idx] = RN[(size_t)t0*400 + idx];
  __syncthreads();
  if (tid >= 150) return;
  float acc[8];
  #pragma unroll
  for (int i=0;i<8;i++) acc[i]=0.f;
  const float4* wr = (const float4*)(fcW + (size_t)tid*400);
  for (int k4=0;k4<100;k4++){
    float4 w = wr[k4];
    #pragma unroll
    for (int tt=0;tt<8;tt++){
      const float4 x4 = *(const float4*)(xs + tt*400 + 4*k4);
      acc[tt] += w.x*x4.x + w.y*x4.y + w.z*x4.z + w.w*x4.w;
    }
  }
  float bb = fcb[tid];
  #pragma unroll
  for (int tt=0;tt<8;tt++)
    out[(size_t)(t0+tt)*150 + tid] = acc[tt] + bb;
}

// ---------------- per-t context scalar ----------------
__global__ void kfinal(const float* __restrict__ RN, const float* __restrict__ actW,
                       const float* __restrict__ actb, const float* __restrict__ Dp,
                       float* __restrict__ vbuf)
{
  int t = blockIdx.x, l = threadIdx.x;
  const float* r = RN + (size_t)t*HID;
  float s0=0.f, s1=0.f, s2=0.f, sd=0.f;
  for (int k=l; k<HID; k+=64){
    float rv = r[k];
    s0 += actW[k]*rv;
    s1 += actW[400+k]*rv;
    s2 += actW[800+k]*rv;
    sd += Dp[k]*rv;
  }
  #pragma unroll
  for (int o=1;o<64;o<<=1){
    s0 += __shfl_xor(s0,o); s1 += __shfl_xor(s1,o);
    s2 += __shfl_xor(s2,o); sd += __shfl_xor(sd,o);
  }
  if (l==0){
    s0 += actb[0]; s1 += actb[1]; s2 += actb[2];
    float m = fmaxf(s0, fmaxf(s1, s2));
    float e0 = __expf(s0-m), e1 = __expf(s1-m), e2 = __expf(s2-m);
    float p0 = e0/(e0+e1+e2);
    vbuf[t] = p0 * fsig(sd);
  }
}

// ---------------- context write (LAST kernel; rewrites whole ctx/scratch region) -------
__global__ void kctx(const float* __restrict__ vbuf, uint4* __restrict__ ctx, int n16){
  int i = blockIdx.x*256 + threadIdx.x;
  int stride = gridDim.x*256;
  for (; i<n16; i+=stride){
    int t = i / 3200;
    int p = i - t*3200;
    uint4 z;
    if (p < 100){
      float v = vbuf[t];
      union{float f; uint32_t u;} cv; cv.f = v;
      z.x = z.y = z.z = z.w = cv.u;
    } else {
      z.x = z.y = z.z = z.w = 0u;
    }
    ctx[i] = z;
  }
}

// ---------------- key LSTM (1 step) + fc ----------------
__global__ void __launch_bounds__(512) kkey(
    const float* __restrict__ RN, const float* __restrict__ Wih,
    const float* __restrict__ bih, const float* __restrict__ bhh,
    const float* __restrict__ fcW, const float* __restrict__ fcb,
    float* __restrict__ out)
{
  __shared__ float rh[HID];
  __shared__ float gk[4*KDIM];
  __shared__ float hk[KDIM];
  int tid = threadIdx.x;
  if (tid < HID) rh[tid] = RN[(size_t)(T_LEN-1)*HID + tid];
  __syncthreads();
  for (int r = tid; r < 4*KDIM; r += 512){
    const float4* wr = (const float4*)(Wih + (size_t)r*HID);
    float acc = 0.f;
    for (int k4=0;k4<100;k4++){
      float4 w = wr[k4];
      const float4 x4 = *(const float4*)(rh + 4*k4);
      acc += w.x*x4.x + w.y*x4.y + w.z*x4.z + w.w*x4.w;
    }
    gk[r] = acc + bih[r] + bhh[r];
  }
  __syncthreads();
  if (tid < KDIM){
    float gi = gk[tid], gg = gk[2*KDIM+tid], go = gk[3*KDIM+tid];
    float cc = fsig(gi)*ftanh(gg);
    hk[tid] = fsig(go)*ftanh(cc);
  }
  __syncthreads();
  if (tid < HID){
    const float4* wr = (const float4*)(fcW + (size_t)tid*KDIM);
    float acc = 0.f;
    for (int k4=0;k4<75;k4++){
      float4 w = wr[k4];
      const float4 x4 = *(const float4*)(hk + 4*k4);
      acc += w.x*x4.x + w.y*x4.y + w.z*x4.z + w.w*x4.w;
    }
    out[tid] = acc + fcb[tid];
  }
}

extern "C" void kernel_launch(void* const* d_in, const int* in_sizes, int n_in,
                              void* d_out, int out_size, void* d_ws, size_t ws_size,
                              hipStream_t stream)
{
  (void)in_sizes; (void)n_in; (void)ws_size;
  const int*   xr   = (const int*)d_in[0];
  const int*   xcpc = (const int*)d_in[1];
  const int*   xma  = (const int*)d_in[2];
  const float* em   = (const float*)d_in[3];
  const float* ec   = (const float*)d_in[4];
  const float* er   = (const float*)d_in[5];
  const float* Wih0 = (const float*)d_in[6];
  const float* Whh0 = (const float*)d_in[7];
  const float* bih0 = (const float*)d_in[8];
  const float* bhh0 = (const float*)d_in[9];
  const float* Wih1 = (const float*)d_in[10];
  const float* Whh1 = (const float*)d_in[11];
  const float* bih1 = (const float*)d_in[12];
  const float* bhh1 = (const float*)d_in[13];
  const float* fcW  = (const float*)d_in[14];
  const float* fcb  = (const float*)d_in[15];
  const float* actW = (const float*)d_in[16];
  const float* actb = (const float*)d_in[17];
  const float* Dp   = (const float*)d_in[18];
  const float* kWih = (const float*)d_in[19];
  /* d_in[20] key_Whh unused: h0 = 0 for the single key step */
  const float* kbih = (const float*)d_in[21];
  const float* kbhh = (const float*)d_in[22];
  const float* kfcW = (const float*)d_in[23];
  const float* kfcb = (const float*)d_in[24];

  float* vbuf = (float*)d_ws;                           // 16 KB

  float* out = (float*)d_out;
  char*  ob  = (char*)d_out;
  size_t total = (size_t)out_size * 4;                  // 212,174,400 bytes
  float* XG0 = (float*)(ob + total - 26214400);         // 4096*1600 f32
  float* RN  = (float*)(ob + total - 32768000);         // 4096*400 f32
  char*  ctl = ob + total - 32768000 - 1048576;         // control block (1 MB reserve)
  // layout: [0..4096) ctl words; hA 102,400 B; hB 102,400 B; g 409,600 B.
  unsigned*           ctlw = (unsigned*)(ctl);
  unsigned long long* hAb  = (unsigned long long*)(ctl + 4096);
  unsigned long long* hBb  = (unsigned long long*)(ctl + 4096 + 102400);
  unsigned long long* gbb  = (unsigned long long*)(ctl + 4096 + 204800);
  int nz = (4096 + 204800 + 409600) / 8;                // 77,312 u64 words

  float* rtok = out;                 // 4096*150
  float* ktok = out + 614400;        // 400
  uint4* ctxp = (uint4*)(ob + 614800u*4u);
  int n16 = (int)((total - 614800u*4u) >> 4);           // 13,107,200

  dim3 gg(T_LEN/8, 7);
  kzero<<<(nz+255)/256,256,0,stream>>>((unsigned long long*)ctl, nz);
  kgemm0<<<gg,256,0,stream>>>(xma, xcpc, xr, em, ec, er, Wih0, bih0, bhh0, XG0);
  kpipe<<<2048,512,0,stream>>>(XG0, Whh0, Whh1, Wih1, bih1, bhh1, RN,
                               hAb, hBb, gbb, ctlw, T_LEN);
  krtoken<<<T_LEN/8,256,0,stream>>>(RN, fcW, fcb, rtok);
  kkey<<<1,512,0,stream>>>(RN, kWih, kbih, kbhh, kfcW, kfcb, ktok);
  kfinal<<<T_LEN,64,0,stream>>>(RN, actW, actb, Dp, vbuf);
  kctx<<<2048,256,0,stream>>>(vbuf, ctxp, n16);
}